// Round 10
// baseline (211.868 us; speedup 1.0000x reference)
//
#include <hip/hip_runtime.h>
#include <hip/hip_bf16.h>
#include <math.h>

// Problem sizes (fixed by reference): B=256, M=64, N=32, D=128, T=64, L=128
#define B_ 256
#define M_ 64
#define N_ 32
#define D_ 128
#define T_ 64
#define L_ 128

typedef __attribute__((ext_vector_type(8))) short short8;   // 8 bf16 = 4 VGPRs (MFMA A/B frag)
typedef __attribute__((ext_vector_type(4))) float floatx4;  // MFMA C/D frag

__device__ __forceinline__ unsigned short f2bf(float f) {
  unsigned int u = __float_as_uint(f);
  unsigned int r = (u + 0x7fffu + ((u >> 16) & 1u)) >> 16;  // RNE
  return (unsigned short)r;
}
__device__ __forceinline__ float bf2f(unsigned short s) {
  return __uint_as_float(((unsigned int)s) << 16);
}
__device__ __forceinline__ float frcp(float x) { return __builtin_amdgcn_rcpf(x); }

// ---------------------------------------------------------------------------
// K1: exact entmax-1.5 over D of route_weights [M,N,D,T] (blocks < 2048),
// PLUS folded prep (blocks >= 2048): x -> bf16 transposed xb2[M][B][D],
// normalize leaves -> LHn bf16, transpose thr -> thrT[N][M] fp32.
// entmax: 4 threads/vector, 10 bisections (2 ILP chains) + exact solve
// (margin 2^-10 -> O(margin^2) ~ 1e-6 error, << bf16).
// ---------------------------------------------------------------------------
__global__ __launch_bounds__(256) void k_entmax(const float* __restrict__ rw,
                                                unsigned short* __restrict__ wq2,
                                                const float* __restrict__ x,
                                                const float* __restrict__ leaves,
                                                unsigned short* __restrict__ xb2,
                                                unsigned short* __restrict__ lhn,
                                                const float* __restrict__ thr,
                                                float* __restrict__ thrT) {
  const int tid = threadIdx.x;
  if (blockIdx.x >= 2048) {  // prep paths
    int bid = blockIdx.x - 2048;
    if (bid < 2048) {
      size_t e = ((size_t)bid * 256 + tid) * 4;
      int b = (int)(e >> 13);        // / (M*D = 8192)
      int rem = (int)(e & 8191);
      int mm = rem >> 7, dd = rem & 127;
      float4 v = *(const float4*)(x + e);
      ushort4 o;
      o.x = f2bf(v.x); o.y = f2bf(v.y); o.z = f2bf(v.z); o.w = f2bf(v.w);
      *(ushort4*)(xb2 + ((size_t)mm * B_ + b) * D_ + dd) = o;
    } else if (bid == 2048) {
      if (tid < L_) {
        const float* r = leaves + tid * T_;
        float ss = 0.f;
        for (int i = 0; i < T_; ++i) ss = fmaf(r[i], r[i], ss);
        float inv = frcp(fmaxf(sqrtf(ss), 1e-12f));
        unsigned short* o = lhn + tid * T_;
        for (int i = 0; i < T_; ++i) o[i] = f2bf(r[i] * inv);
      }
    } else {  // thr transpose: thrT[n][m] = thr[m][n]
#pragma unroll
      for (int k = 0; k < 8; ++k) {
        int idx = k * 256 + tid;         // idx = n*64+m
        int nn = idx >> 6, mm = idx & 63;
        thrT[idx] = thr[mm * N_ + nn];
      }
    }
    return;
  }

  const int gv = blockIdx.x * 64 + (tid >> 2);  // vector id = (m*N+n)*T + t
  const int h = tid & 3;                        // quarter of D
  const int mn = gv >> 6;
  const int t = gv & 63;
  const float* base = rw + ((size_t)mn * D_ + h * 32) * T_ + t;
  float xv_[32];
#pragma unroll
  for (int i = 0; i < 32; ++i) xv_[i] = base[(size_t)i * T_];
  float mx = xv_[0];
#pragma unroll
  for (int i = 1; i < 32; ++i) mx = fmaxf(mx, xv_[i]);
  mx = fmaxf(mx, __shfl_xor(mx, 1));
  mx = fmaxf(mx, __shfl_xor(mx, 2));
#pragma unroll
  for (int i = 0; i < 32; ++i) xv_[i] = (xv_[i] - mx) * 0.5f;

  float lo = -1.0f, hi = 0.0f;
  for (int it = 0; it < 10; ++it) {
    float tau = 0.5f * (lo + hi);
    float f0 = 0.0f, f1 = 0.0f;  // 2 ILP chains
#pragma unroll
    for (int i = 0; i < 16; ++i) {
      float u0 = fmaxf(xv_[2 * i] - tau, 0.0f);
      float u1 = fmaxf(xv_[2 * i + 1] - tau, 0.0f);
      f0 = fmaf(u0, u0, f0);
      f1 = fmaf(u1, u1, f1);
    }
    float f = f0 + f1;
    f += __shfl_xor(f, 1);
    f += __shfl_xor(f, 2);
    if (f >= 1.0f) lo = tau; else hi = tau;
  }
  float tau0 = 0.5f * (lo + hi);
  float cnt = 0.f, s1 = 0.f, s2 = 0.f;
#pragma unroll
  for (int i = 0; i < 32; ++i) {
    bool in = xv_[i] > tau0;
    float q = in ? xv_[i] : 0.0f;
    cnt += in ? 1.0f : 0.0f;
    s1 += q;
    s2 = fmaf(q, q, s2);
  }
  cnt += __shfl_xor(cnt, 1); cnt += __shfl_xor(cnt, 2);
  s1 += __shfl_xor(s1, 1);   s1 += __shfl_xor(s1, 2);
  s2 += __shfl_xor(s2, 1);   s2 += __shfl_xor(s2, 2);
  float rc = frcp(cnt);
  float mean = s1 * rc;
  float ss = s2 - mean * s1;
  float delta = (1.0f - ss) * rc;
  float tau = mean - sqrtf(fmaxf(delta, 0.0f));

  unsigned short pv[32];
#pragma unroll
  for (int i = 0; i < 32; ++i) {
    float u = fmaxf(xv_[i] - tau, 0.0f);
    pv[i] = f2bf(u * u);
  }
  uint4* o = (uint4*)(wq2 + (size_t)gv * D_ + h * 32);
#pragma unroll
  for (int j = 0; j < 4; ++j) {
    uint4 w;
    w.x = (unsigned)pv[8 * j + 0] | ((unsigned)pv[8 * j + 1] << 16);
    w.y = (unsigned)pv[8 * j + 2] | ((unsigned)pv[8 * j + 3] << 16);
    w.z = (unsigned)pv[8 * j + 4] | ((unsigned)pv[8 * j + 5] << 16);
    w.w = (unsigned)pv[8 * j + 6] | ((unsigned)pv[8 * j + 7] << 16);
    o[j] = w;
  }
}

// ---------------------------------------------------------------------------
// K2 (R10): priors GEMM with SWAPPED operands: A = W (t rows, from LDS),
// B = x (b cols, direct from xb2 global) => C[row=t][col=b]; each lane holds
// 4 CONSECUTIVE t for one b -> direct ushort4 store to priors[n][g][m][bq][t].
// Kills the Ct LDS transpose + 2 barriers (R9's latency chain). ONE barrier.
// LDS 17.4KB; ~50 VGPR -> 6 waves/SIMD.
// ---------------------------------------------------------------------------
#define BS_STRIDE 136
__global__ __launch_bounds__(256, 6) void k_priors(const unsigned short* __restrict__ xb2,
                                                   const unsigned short* __restrict__ wq2,
                                                   unsigned short* __restrict__ priors) {
  const int m = blockIdx.x, n = blockIdx.y;
  const int tid = threadIdx.x;
  const int wid = tid >> 6, lane = tid & 63;
  const int row16 = lane & 15, quad = lane >> 4;
  __shared__ __align__(16) unsigned short Bs[64 * BS_STRIDE];  // W-tile [t][d]

  const unsigned short* bsrc = wq2 + ((size_t)(m * N_ + n) * T_) * D_;  // 64x128 contiguous
  {
    int tr = tid >> 4;
    int c = tid & 15;
#pragma unroll
    for (int p = 0; p < 4; ++p) {
      int row = p * 16 + tr;
      uint4 v = *(const uint4*)(bsrc + row * D_ + c * 8);
      *(uint4*)&Bs[row * BS_STRIDE + c * 8] = v;
    }
  }
  __syncthreads();  // the only barrier

  const int b = wid * 64 + row16;  // +sub*16 below; lane's B-operand column
#pragma unroll
  for (int sub = 0; sub < 4; ++sub) {
    const int bb = b + sub * 16;
    const unsigned short* xptr = xb2 + ((size_t)m * B_ + bb) * D_ + quad * 8;
    short8 bfr[4];
#pragma unroll
    for (int ks = 0; ks < 4; ++ks) bfr[ks] = *(const short8*)(xptr + ks * 32);

    unsigned short* dstb = priors +
        ((((size_t)n * 32 + (bb >> 3)) * M_ + m) * 8 + (bb & 7)) * T_ + quad * 4;
#pragma unroll
    for (int cf = 0; cf < 4; ++cf) {
      floatx4 acc = (floatx4){0.f, 0.f, 0.f, 0.f};
#pragma unroll
      for (int ks = 0; ks < 4; ++ks) {
        short8 afr = *(const short8*)&Bs[(cf * 16 + row16) * BS_STRIDE + ks * 32 + quad * 8];
        acc = __builtin_amdgcn_mfma_f32_16x16x32_bf16(afr, bfr[ks], acc, 0, 0, 0);
      }
      ushort4 o4;
      o4.x = f2bf(acc[0]); o4.y = f2bf(acc[1]);
      o4.z = f2bf(acc[2]); o4.w = f2bf(acc[3]);
      *(ushort4*)(dstb + cf * 16) = o4;  // t = cf*16 + quad*4 .. +3
    }
  }
}

// ---------------------------------------------------------------------------
// K3 (unchanged from R9): block = (n, g4); wave owns ONE b. No LDS staging,
// no barriers; rcp-based sigmoid/softmax; weighted sum reuses afr registers.
// ---------------------------------------------------------------------------
__global__ __launch_bounds__(256, 4) void k_route(const unsigned short* __restrict__ priors,
                                                  const unsigned short* __restrict__ lhn,
                                                  const float* __restrict__ thrT,
                                                  const float* __restrict__ gamma,
                                                  const float* __restrict__ beta,
                                                  float* __restrict__ out) {
  const int n = blockIdx.x, g4 = blockIdx.y;
  const int tid = threadIdx.x;
  const int wid = tid >> 6, lane = tid & 63;
  const int col = lane & 15, quad = lane >> 4;

  __shared__ float probL[4][64];

  const int g = g4 >> 1;
  const int bq = (g4 & 1) * 4 + wid;  // position within the g8 slab

  const unsigned short* base = priors + (((size_t)n * 32 + g) * M_) * 512 + bq * T_;
  short8 afr[4][2];  // A[m = mt*16+col][k(t) = ks*32+quad*8+j]
#pragma unroll
  for (int mt = 0; mt < 4; ++mt)
#pragma unroll
    for (int ks = 0; ks < 2; ++ks)
      afr[mt][ks] = *(const short8*)(base + (size_t)(mt * 16 + col) * 512 + ks * 32 + quad * 8);

  float thv = thrT[n * 64 + lane];  // coalesced; redistributed via shfl below

  float dis[4][4];
#pragma unroll
  for (int mt = 0; mt < 4; ++mt)
#pragma unroll
    for (int r = 0; r < 4; ++r) dis[mt][r] = 0.f;

#pragma unroll
  for (int s4 = 0; s4 < 4; ++s4) {  // l-slice of 32
    floatx4 acc[4][2];  // C[m = mt*16+quad*4+r][l = s4*32+lt*16+col]
#pragma unroll
    for (int mt = 0; mt < 4; ++mt)
#pragma unroll
      for (int lt = 0; lt < 2; ++lt) acc[mt][lt] = (floatx4){0.f, 0.f, 0.f, 0.f};

#pragma unroll
    for (int lt = 0; lt < 2; ++lt) {
#pragma unroll
      for (int ks = 0; ks < 2; ++ks) {
        short8 bfr = *(const short8*)(lhn + (s4 * 32 + lt * 16 + col) * T_ + ks * 32 + quad * 8);
#pragma unroll
        for (int mt = 0; mt < 4; ++mt)
          acc[mt][lt] = __builtin_amdgcn_mfma_f32_16x16x32_bf16(afr[mt][ks], bfr, acc[mt][lt], 0, 0, 0);
      }
    }

#pragma unroll
    for (int mt = 0; mt < 4; ++mt)
#pragma unroll
      for (int lt = 0; lt < 2; ++lt)
#pragma unroll
        for (int r = 0; r < 4; ++r)
          acc[mt][lt][r] = frcp(1.0f + __expf(-acc[mt][lt][r]));

    float mc[2];
#pragma unroll
    for (int lt = 0; lt < 2; ++lt) {
      float s = 0.f;
#pragma unroll
      for (int mt = 0; mt < 4; ++mt)
#pragma unroll
        for (int r = 0; r < 4; ++r) s += acc[mt][lt][r];
      s += __shfl_xor(s, 16);
      s += __shfl_xor(s, 32);
      mc[lt] = s * (1.0f / 64.0f);
    }

#pragma unroll
    for (int mt = 0; mt < 4; ++mt)
#pragma unroll
      for (int r = 0; r < 4; ++r) {
        float s = 0.f;
#pragma unroll
        for (int lt = 0; lt < 2; ++lt) {
          float df = acc[mt][lt][r] - mc[lt];
          s = fmaf(df, df, s);
        }
        dis[mt][r] += s;
      }
  }

#pragma unroll
  for (int off = 1; off <= 8; off <<= 1)
#pragma unroll
    for (int mt = 0; mt < 4; ++mt)
#pragma unroll
      for (int r = 0; r < 4; ++r) dis[mt][r] += __shfl_xor(dis[mt][r], off);

  float e[4][4];
  float mxw = 0.f;
#pragma unroll
  for (int mt = 0; mt < 4; ++mt)
#pragma unroll
    for (int r = 0; r < 4; ++r) {
      float th = __shfl(thv, mt * 16 + quad * 4 + r);
      float w = fmaxf(th * th - dis[mt][r] * (1.0f / 128.0f), 0.0f);
      e[mt][r] = w;
      mxw = fmaxf(mxw, w);
    }
  mxw = fmaxf(mxw, __shfl_xor(mxw, 16));
  mxw = fmaxf(mxw, __shfl_xor(mxw, 32));
  float ssum = 0.f;
#pragma unroll
  for (int mt = 0; mt < 4; ++mt)
#pragma unroll
    for (int r = 0; r < 4; ++r) {
      e[mt][r] = __expf(e[mt][r] - mxw);
      ssum += e[mt][r];
    }
  ssum += __shfl_xor(ssum, 16);
  ssum += __shfl_xor(ssum, 32);
  float inv = frcp(ssum);
  if (col == 0) {
#pragma unroll
    for (int mt = 0; mt < 4; ++mt)
#pragma unroll
      for (int r = 0; r < 4; ++r)
        probL[wid][mt * 16 + quad * 4 + r] = e[mt][r] * inv;
  }
  // same-wave LDS write->read: compiler inserts lgkmcnt wait (no barrier)

  float pr[4];
#pragma unroll
  for (int mt = 0; mt < 4; ++mt) pr[mt] = probL[wid][mt * 16 + col];

  float o[2][8];
#pragma unroll
  for (int ks = 0; ks < 2; ++ks)
#pragma unroll
    for (int j = 0; j < 8; ++j) o[ks][j] = 0.f;
#pragma unroll
  for (int mt = 0; mt < 4; ++mt)
#pragma unroll
    for (int ks = 0; ks < 2; ++ks)
#pragma unroll
      for (int j = 0; j < 8; ++j)
        o[ks][j] = fmaf(pr[mt], bf2f((unsigned short)afr[mt][ks][j]), o[ks][j]);
#pragma unroll
  for (int off = 1; off <= 8; off <<= 1)
#pragma unroll
    for (int ks = 0; ks < 2; ++ks)
#pragma unroll
      for (int j = 0; j < 8; ++j) o[ks][j] += __shfl_xor(o[ks][j], off);

  float mu = 0.f;
#pragma unroll
  for (int ks = 0; ks < 2; ++ks)
#pragma unroll
    for (int j = 0; j < 8; ++j) mu += o[ks][j];
  mu += __shfl_xor(mu, 16);
  mu += __shfl_xor(mu, 32);
  mu *= (1.0f / 64.0f);
  float var = 0.f;
#pragma unroll
  for (int ks = 0; ks < 2; ++ks)
#pragma unroll
    for (int j = 0; j < 8; ++j) {
      float d = o[ks][j] - mu;
      o[ks][j] = d;
      var = fmaf(d, d, var);
    }
  var += __shfl_xor(var, 16);
  var += __shfl_xor(var, 32);
  var *= (1.0f / 64.0f);
  float rstd = rsqrtf(var + 1e-5f);

  if (col == 0) {
    const int b = g4 * 4 + wid;
    float* obase = out + ((size_t)b * N_ + n) * T_;
#pragma unroll
    for (int ks = 0; ks < 2; ++ks) {
      int tb = ks * 32 + quad * 8;
      float4 g0 = *(const float4*)(gamma + tb);
      float4 g1 = *(const float4*)(gamma + tb + 4);
      float4 b0 = *(const float4*)(beta + tb);
      float4 b1 = *(const float4*)(beta + tb + 4);
      float4 r0, r1;
      r0.x = o[ks][0] * rstd * g0.x + b0.x;
      r0.y = o[ks][1] * rstd * g0.y + b0.y;
      r0.z = o[ks][2] * rstd * g0.z + b0.z;
      r0.w = o[ks][3] * rstd * g0.w + b0.w;
      r1.x = o[ks][4] * rstd * g1.x + b1.x;
      r1.y = o[ks][5] * rstd * g1.y + b1.y;
      r1.z = o[ks][6] * rstd * g1.z + b1.z;
      r1.w = o[ks][7] * rstd * g1.w + b1.w;
      *(float4*)(obase + tb) = r0;
      *(float4*)(obase + tb + 4) = r1;
    }
  }
}

// ---------------------------------------------------------------------------
// Workspace layout (bytes):
//   Wq2    [M][N][T][D]      bf16 : off 0,           33,554,432
//   priors [N][G32][M][8][T] bf16 : off 33,554,432,  67,108,864
//   xb2    [M][B][D]         bf16 : off 100,663,296,  4,194,304
//   LHn    [L][T]            bf16 : off 104,857,600,     16,384
//   thrT   [N][M]            fp32 : off 104,873,984,      8,192
// ---------------------------------------------------------------------------
extern "C" void kernel_launch(void* const* d_in, const int* in_sizes, int n_in,
                              void* d_out, int out_size, void* d_ws, size_t ws_size,
                              hipStream_t stream) {
  const float* x = (const float*)d_in[0];
  const float* rw = (const float*)d_in[1];
  const float* thr = (const float*)d_in[2];
  const float* leaves = (const float*)d_in[3];
  const float* gamma = (const float*)d_in[4];
  const float* beta = (const float*)d_in[5];
  float* out = (float*)d_out;

  char* ws = (char*)d_ws;
  unsigned short* wq2 = (unsigned short*)(ws);
  unsigned short* priors = (unsigned short*)(ws + 33554432);
  unsigned short* xb2 = (unsigned short*)(ws + 33554432 + 67108864);
  unsigned short* lhn = (unsigned short*)(ws + 100663296 + 4194304);
  float* thrT = (float*)(ws + 104857600 + 16384);

  hipLaunchKernelGGL(k_entmax, dim3(4098), dim3(256), 0, stream, rw, wq2, x, leaves, xb2, lhn, thr, thrT);
  hipLaunchKernelGGL(k_priors, dim3(64, 32), dim3(256), 0, stream, xb2, wq2, priors);
  hipLaunchKernelGGL(k_route, dim3(32, 64), dim3(256), 0, stream, priors, lhn, thrT, gamma, beta, out);
}

// Round 11
// 186.842 us; speedup vs baseline: 1.1339x; 1.1339x over previous
//
#include <hip/hip_runtime.h>
#include <hip/hip_bf16.h>
#include <math.h>

// Problem sizes (fixed by reference): B=256, M=64, N=32, D=128, T=64, L=128
#define B_ 256
#define M_ 64
#define N_ 32
#define D_ 128
#define T_ 64
#define L_ 128

typedef __attribute__((ext_vector_type(8))) short short8;   // 8 bf16 = 4 VGPRs (MFMA A/B frag)
typedef __attribute__((ext_vector_type(4))) float floatx4;  // MFMA C/D frag

__device__ __forceinline__ unsigned short f2bf(float f) {
  unsigned int u = __float_as_uint(f);
  unsigned int r = (u + 0x7fffu + ((u >> 16) & 1u)) >> 16;  // RNE
  return (unsigned short)r;
}
__device__ __forceinline__ float bf2f(unsigned short s) {
  return __uint_as_float(((unsigned int)s) << 16);
}
__device__ __forceinline__ float frcp(float x) { return __builtin_amdgcn_rcpf(x); }

// ---------------------------------------------------------------------------
// K1 (R11 rewrite): exact entmax-1.5 over D of route_weights [M,N,D,T].
// NEW thread mapping to kill the VMEM-instr bottleneck: each thread owns
// FOUR vectors (t..t+3) x 16 d's -> rw loads are float4 ALONG T (16 loads of
// 16B forming 128B segments, vs 32 scalar 4B loads before). d per thread =
// {8i+j : i=0..15}, j = lane&7; reductions over d = 3-round shfl_xor(1,2,4).
// wq2/xb2 rows store d in PI-PERMUTED order pi(8i+j)=16j+i — consistent on
// both GEMM operands, so priors values are unchanged (dot reassociation).
// Prep paths (blocks >= 1024): xb2 pi-transposed cast, leaves norm, thrT.
// ---------------------------------------------------------------------------
__global__ __launch_bounds__(256) void k_entmax(const float* __restrict__ rw,
                                                unsigned short* __restrict__ wq2,
                                                const float* __restrict__ x,
                                                const float* __restrict__ leaves,
                                                unsigned short* __restrict__ xb2,
                                                unsigned short* __restrict__ lhn,
                                                const float* __restrict__ thr,
                                                float* __restrict__ thrT) {
  const int tid = threadIdx.x;
  const int bx = blockIdx.x;
  if (bx >= 1024) {  // prep paths
    int bid = bx - 1024;
    if (bid < 512) {
      // xb2[m][b][pi(d)] = x[b][m][d], pi(8i+j) = 16j+i
      int idx = bid * 256 + tid;         // (m, b, j)
      int j = idx & 7, b = (idx >> 3) & 255, m = idx >> 11;
      const float* xs = x + ((size_t)b * M_ + m) * D_ + j;
      unsigned short pv[16];
#pragma unroll
      for (int i = 0; i < 16; ++i) pv[i] = f2bf(xs[i * 8]);
      unsigned short* dst = xb2 + ((size_t)m * B_ + b) * D_ + j * 16;
      uint4 w0, w1;
      w0.x = pv[0] | ((unsigned)pv[1] << 16);  w0.y = pv[2] | ((unsigned)pv[3] << 16);
      w0.z = pv[4] | ((unsigned)pv[5] << 16);  w0.w = pv[6] | ((unsigned)pv[7] << 16);
      w1.x = pv[8] | ((unsigned)pv[9] << 16);  w1.y = pv[10] | ((unsigned)pv[11] << 16);
      w1.z = pv[12] | ((unsigned)pv[13] << 16); w1.w = pv[14] | ((unsigned)pv[15] << 16);
      *(uint4*)(dst) = w0;
      *(uint4*)(dst + 8) = w1;
    } else if (bid == 512) {
      if (tid < L_) {
        const float* r = leaves + tid * T_;
        float ss = 0.f;
        for (int i = 0; i < T_; ++i) ss = fmaf(r[i], r[i], ss);
        float inv = frcp(fmaxf(sqrtf(ss), 1e-12f));
        unsigned short* o = lhn + tid * T_;
        for (int i = 0; i < T_; ++i) o[i] = f2bf(r[i] * inv);
      }
    } else {  // thrT[n][m] = thr[m][n]
#pragma unroll
      for (int k = 0; k < 8; ++k) {
        int idx = k * 256 + tid;
        int nn = idx >> 6, mm = idx & 63;
        thrT[idx] = thr[mm * N_ + nn];
      }
    }
    return;
  }

  // entmax main: block covers 2 mn's; 128 threads per mn.
  const int mn = bx * 2 + (tid >> 7);
  const int sub = tid & 127;
  const int g = sub >> 3;   // t-group: lane's 4 t's are 4g..4g+3
  const int j = sub & 7;    // d-lane: d = 8i + j
  const float* base = rw + (size_t)mn * D_ * T_ + g * 4;

  floatx4 xv[16];
#pragma unroll
  for (int i = 0; i < 16; ++i)
    xv[i] = *(const floatx4*)(base + (size_t)(i * 8 + j) * T_);

  floatx4 mx = xv[0];
#pragma unroll
  for (int i = 1; i < 16; ++i)
#pragma unroll
    for (int c = 0; c < 4; ++c) mx[c] = fmaxf(mx[c], xv[i][c]);
#pragma unroll
  for (int off = 1; off <= 4; off <<= 1)
#pragma unroll
    for (int c = 0; c < 4; ++c) mx[c] = fmaxf(mx[c], __shfl_xor(mx[c], off));
#pragma unroll
  for (int i = 0; i < 16; ++i)
#pragma unroll
    for (int c = 0; c < 4; ++c) xv[i][c] = (xv[i][c] - mx[c]) * 0.5f;

  floatx4 lo = (floatx4){-1.f, -1.f, -1.f, -1.f};
  floatx4 hi = (floatx4){0.f, 0.f, 0.f, 0.f};
  for (int it = 0; it < 10; ++it) {
    floatx4 tau, f = (floatx4){0.f, 0.f, 0.f, 0.f};
#pragma unroll
    for (int c = 0; c < 4; ++c) tau[c] = 0.5f * (lo[c] + hi[c]);
#pragma unroll
    for (int i = 0; i < 16; ++i)
#pragma unroll
      for (int c = 0; c < 4; ++c) {
        float u = fmaxf(xv[i][c] - tau[c], 0.0f);
        f[c] = fmaf(u, u, f[c]);
      }
#pragma unroll
    for (int off = 1; off <= 4; off <<= 1)
#pragma unroll
      for (int c = 0; c < 4; ++c) f[c] += __shfl_xor(f[c], off);
#pragma unroll
    for (int c = 0; c < 4; ++c) {
      bool ge = f[c] >= 1.0f;
      lo[c] = ge ? tau[c] : lo[c];
      hi[c] = ge ? hi[c] : tau[c];
    }
  }
  floatx4 tau0, cnt = (floatx4){0,0,0,0}, s1 = (floatx4){0,0,0,0}, s2 = (floatx4){0,0,0,0};
#pragma unroll
  for (int c = 0; c < 4; ++c) tau0[c] = 0.5f * (lo[c] + hi[c]);
#pragma unroll
  for (int i = 0; i < 16; ++i)
#pragma unroll
    for (int c = 0; c < 4; ++c) {
      bool in = xv[i][c] > tau0[c];
      float q = in ? xv[i][c] : 0.0f;
      cnt[c] += in ? 1.0f : 0.0f;
      s1[c] += q;
      s2[c] = fmaf(q, q, s2[c]);
    }
#pragma unroll
  for (int off = 1; off <= 4; off <<= 1)
#pragma unroll
    for (int c = 0; c < 4; ++c) {
      cnt[c] += __shfl_xor(cnt[c], off);
      s1[c] += __shfl_xor(s1[c], off);
      s2[c] += __shfl_xor(s2[c], off);
    }
  floatx4 tau;
#pragma unroll
  for (int c = 0; c < 4; ++c) {
    float rc = frcp(cnt[c]);
    float mean = s1[c] * rc;
    float ss = s2[c] - mean * s1[c];
    float delta = (1.0f - ss) * rc;
    tau[c] = mean - sqrtf(fmaxf(delta, 0.0f));
  }

  // store: per t (c), thread's 16 d's occupy pi positions [16j, 16j+16)
#pragma unroll
  for (int c = 0; c < 4; ++c) {
    unsigned short pv[16];
#pragma unroll
    for (int i = 0; i < 16; ++i) {
      float u = fmaxf(xv[i][c] - tau[c], 0.0f);
      pv[i] = f2bf(u * u);
    }
    unsigned short* dst = wq2 + ((size_t)mn * 64 + g * 4 + c) * D_ + j * 16;
    uint4 w0, w1;
    w0.x = pv[0] | ((unsigned)pv[1] << 16);  w0.y = pv[2] | ((unsigned)pv[3] << 16);
    w0.z = pv[4] | ((unsigned)pv[5] << 16);  w0.w = pv[6] | ((unsigned)pv[7] << 16);
    w1.x = pv[8] | ((unsigned)pv[9] << 16);  w1.y = pv[10] | ((unsigned)pv[11] << 16);
    w1.z = pv[12] | ((unsigned)pv[13] << 16); w1.w = pv[14] | ((unsigned)pv[15] << 16);
    *(uint4*)(dst) = w0;
    *(uint4*)(dst + 8) = w1;
  }
}

// ---------------------------------------------------------------------------
// K2 (R11): R9 transpose-store structure + swapped operands feeding it:
// A = W (t rows, LDS, shared by both b-subtiles), B = x (b cols, global,
// ALL 16 xfr loads issued up-front => chunk-1 loads in flight during chunk-0
// compute). C[row=t][col=b]: lane holds 4 consecutive t for one b -> Ct write
// is ONE ds_write_b64 per tile (was 16 scalar b16). Stores stay 1KB-contig.
// LDS 35.8KB -> 4 blocks/CU; VGPR ~110 under (256,4).
// ---------------------------------------------------------------------------
#define BS_STRIDE 136
__global__ __launch_bounds__(256, 4) void k_priors(const unsigned short* __restrict__ xb2,
                                                   const unsigned short* __restrict__ wq2,
                                                   unsigned short* __restrict__ priors) {
  const int n = blockIdx.x, m = blockIdx.y;
  const int tid = threadIdx.x;
  const int wid = tid >> 6, lane = tid & 63;
  const int row16 = lane & 15, quad = lane >> 4;
  __shared__ __align__(16) unsigned short Bs[64 * BS_STRIDE];  // W [t][pi_d]
  __shared__ __align__(16) unsigned short Ct[128 * 72];        // [b][t]

  // issue ALL B-operand (x) loads first: b = c*128 + wid*32 + sub*16 + row16
  short8 xfr[2][2][4];
#pragma unroll
  for (int c = 0; c < 2; ++c)
#pragma unroll
    for (int sub = 0; sub < 2; ++sub) {
      const int b = c * 128 + wid * 32 + sub * 16 + row16;
      const unsigned short* xptr = xb2 + ((size_t)m * B_ + b) * D_ + quad * 8;
#pragma unroll
      for (int ks = 0; ks < 4; ++ks) xfr[c][sub][ks] = *(const short8*)(xptr + ks * 32);
    }

  {  // stage W tile into LDS
    const unsigned short* bsrc = wq2 + ((size_t)(m * N_ + n) * T_) * D_;
    int tr = tid >> 4, cc = tid & 15;
#pragma unroll
    for (int p = 0; p < 4; ++p) {
      int row = p * 16 + tr;
      uint4 v = *(const uint4*)(bsrc + row * D_ + cc * 8);
      *(uint4*)&Bs[row * BS_STRIDE + cc * 8] = v;
    }
  }
  __syncthreads();

#pragma unroll
  for (int c = 0; c < 2; ++c) {  // chunk of 128 b
    floatx4 acc[2][4];
#pragma unroll
    for (int sub = 0; sub < 2; ++sub)
#pragma unroll
      for (int cf = 0; cf < 4; ++cf) acc[sub][cf] = (floatx4){0.f, 0.f, 0.f, 0.f};

#pragma unroll
    for (int cf = 0; cf < 4; ++cf) {
      short8 afr[4];
#pragma unroll
      for (int ks = 0; ks < 4; ++ks)
        afr[ks] = *(const short8*)&Bs[(cf * 16 + row16) * BS_STRIDE + ks * 32 + quad * 8];
#pragma unroll
      for (int ks = 0; ks < 4; ++ks)
#pragma unroll
        for (int sub = 0; sub < 2; ++sub)
          acc[sub][cf] = __builtin_amdgcn_mfma_f32_16x16x32_bf16(afr[ks], xfr[c][sub][ks], acc[sub][cf], 0, 0, 0);
    }

    if (c) __syncthreads();  // chunk-0 store phase must be done with Ct
    // Ct write: lane holds t = cf*16+quad*4..+3 for b_local = wid*32+sub*16+row16
#pragma unroll
    for (int sub = 0; sub < 2; ++sub)
#pragma unroll
      for (int cf = 0; cf < 4; ++cf) {
        ushort4 o4;
        o4.x = f2bf(acc[sub][cf][0]); o4.y = f2bf(acc[sub][cf][1]);
        o4.z = f2bf(acc[sub][cf][2]); o4.w = f2bf(acc[sub][cf][3]);
        *(ushort4*)&Ct[(wid * 32 + sub * 16 + row16) * 72 + cf * 16 + quad * 4] = o4;
      }
    __syncthreads();

    {  // store 128 rows x 128B; 16 lanes = one 1KB contiguous chunk
      int q = tid >> 4, s = tid & 15;
      int row = q * 8 + (s >> 1);
      int half = s & 1;
      const unsigned short* src = &Ct[row * 72 + half * 32];
      unsigned short* dst = priors +
          ((((size_t)n * 32 + c * 16 + q) * M_ + m) * 8 + (s >> 1)) * T_ + half * 32;
      uint4 a0 = *(const uint4*)(src);
      uint4 a1 = *(const uint4*)(src + 8);
      uint4 a2 = *(const uint4*)(src + 16);
      uint4 a3 = *(const uint4*)(src + 24);
      *(uint4*)(dst) = a0;
      *(uint4*)(dst + 8) = a1;
      *(uint4*)(dst + 16) = a2;
      *(uint4*)(dst + 24) = a3;
    }
  }
}

// ---------------------------------------------------------------------------
// K3 (unchanged from R9/R10): block = (n, g4); wave owns ONE b. No LDS
// staging, no barriers; rcp sigmoid/softmax; weighted sum reuses afr regs.
// ---------------------------------------------------------------------------
__global__ __launch_bounds__(256, 4) void k_route(const unsigned short* __restrict__ priors,
                                                  const unsigned short* __restrict__ lhn,
                                                  const float* __restrict__ thrT,
                                                  const float* __restrict__ gamma,
                                                  const float* __restrict__ beta,
                                                  float* __restrict__ out) {
  const int n = blockIdx.x, g4 = blockIdx.y;
  const int tid = threadIdx.x;
  const int wid = tid >> 6, lane = tid & 63;
  const int col = lane & 15, quad = lane >> 4;

  __shared__ float probL[4][64];

  const int g = g4 >> 1;
  const int bq = (g4 & 1) * 4 + wid;

  const unsigned short* base = priors + (((size_t)n * 32 + g) * M_) * 512 + bq * T_;
  short8 afr[4][2];  // A[m = mt*16+col][k(t) = ks*32+quad*8+j]
#pragma unroll
  for (int mt = 0; mt < 4; ++mt)
#pragma unroll
    for (int ks = 0; ks < 2; ++ks)
      afr[mt][ks] = *(const short8*)(base + (size_t)(mt * 16 + col) * 512 + ks * 32 + quad * 8);

  float thv = thrT[n * 64 + lane];

  float dis[4][4];
#pragma unroll
  for (int mt = 0; mt < 4; ++mt)
#pragma unroll
    for (int r = 0; r < 4; ++r) dis[mt][r] = 0.f;

#pragma unroll
  for (int s4 = 0; s4 < 4; ++s4) {
    floatx4 acc[4][2];
#pragma unroll
    for (int mt = 0; mt < 4; ++mt)
#pragma unroll
      for (int lt = 0; lt < 2; ++lt) acc[mt][lt] = (floatx4){0.f, 0.f, 0.f, 0.f};

#pragma unroll
    for (int lt = 0; lt < 2; ++lt) {
#pragma unroll
      for (int ks = 0; ks < 2; ++ks) {
        short8 bfr = *(const short8*)(lhn + (s4 * 32 + lt * 16 + col) * T_ + ks * 32 + quad * 8);
#pragma unroll
        for (int mt = 0; mt < 4; ++mt)
          acc[mt][lt] = __builtin_amdgcn_mfma_f32_16x16x32_bf16(afr[mt][ks], bfr, acc[mt][lt], 0, 0, 0);
      }
    }

#pragma unroll
    for (int mt = 0; mt < 4; ++mt)
#pragma unroll
      for (int lt = 0; lt < 2; ++lt)
#pragma unroll
        for (int r = 0; r < 4; ++r)
          acc[mt][lt][r] = frcp(1.0f + __expf(-acc[mt][lt][r]));

    float mc[2];
#pragma unroll
    for (int lt = 0; lt < 2; ++lt) {
      float s = 0.f;
#pragma unroll
      for (int mt = 0; mt < 4; ++mt)
#pragma unroll
        for (int r = 0; r < 4; ++r) s += acc[mt][lt][r];
      s += __shfl_xor(s, 16);
      s += __shfl_xor(s, 32);
      mc[lt] = s * (1.0f / 64.0f);
    }

#pragma unroll
    for (int mt = 0; mt < 4; ++mt)
#pragma unroll
      for (int r = 0; r < 4; ++r) {
        float s = 0.f;
#pragma unroll
        for (int lt = 0; lt < 2; ++lt) {
          float df = acc[mt][lt][r] - mc[lt];
          s = fmaf(df, df, s);
        }
        dis[mt][r] += s;
      }
  }

#pragma unroll
  for (int off = 1; off <= 8; off <<= 1)
#pragma unroll
    for (int mt = 0; mt < 4; ++mt)
#pragma unroll
      for (int r = 0; r < 4; ++r) dis[mt][r] += __shfl_xor(dis[mt][r], off);

  float e[4][4];
  float mxw = 0.f;
#pragma unroll
  for (int mt = 0; mt < 4; ++mt)
#pragma unroll
    for (int r = 0; r < 4; ++r) {
      float th = __shfl(thv, mt * 16 + quad * 4 + r);
      float w = fmaxf(th * th - dis[mt][r] * (1.0f / 128.0f), 0.0f);
      e[mt][r] = w;
      mxw = fmaxf(mxw, w);
    }
  mxw = fmaxf(mxw, __shfl_xor(mxw, 16));
  mxw = fmaxf(mxw, __shfl_xor(mxw, 32));
  float ssum = 0.f;
#pragma unroll
  for (int mt = 0; mt < 4; ++mt)
#pragma unroll
    for (int r = 0; r < 4; ++r) {
      e[mt][r] = __expf(e[mt][r] - mxw);
      ssum += e[mt][r];
    }
  ssum += __shfl_xor(ssum, 16);
  ssum += __shfl_xor(ssum, 32);
  float inv = frcp(ssum);
  if (col == 0) {
#pragma unroll
    for (int mt = 0; mt < 4; ++mt)
#pragma unroll
      for (int r = 0; r < 4; ++r)
        probL[wid][mt * 16 + quad * 4 + r] = e[mt][r] * inv;
  }
  // same-wave LDS write->read: compiler inserts lgkmcnt wait (no barrier)

  float pr[4];
#pragma unroll
  for (int mt = 0; mt < 4; ++mt) pr[mt] = probL[wid][mt * 16 + col];

  float o[2][8];
#pragma unroll
  for (int ks = 0; ks < 2; ++ks)
#pragma unroll
    for (int j = 0; j < 8; ++j) o[ks][j] = 0.f;
#pragma unroll
  for (int mt = 0; mt < 4; ++mt)
#pragma unroll
    for (int ks = 0; ks < 2; ++ks)
#pragma unroll
      for (int j = 0; j < 8; ++j)
        o[ks][j] = fmaf(pr[mt], bf2f((unsigned short)afr[mt][ks][j]), o[ks][j]);
#pragma unroll
  for (int off = 1; off <= 8; off <<= 1)
#pragma unroll
    for (int ks = 0; ks < 2; ++ks)
#pragma unroll
      for (int j = 0; j < 8; ++j) o[ks][j] += __shfl_xor(o[ks][j], off);

  float mu = 0.f;
#pragma unroll
  for (int ks = 0; ks < 2; ++ks)
#pragma unroll
    for (int j = 0; j < 8; ++j) mu += o[ks][j];
  mu += __shfl_xor(mu, 16);
  mu += __shfl_xor(mu, 32);
  mu *= (1.0f / 64.0f);
  float var = 0.f;
#pragma unroll
  for (int ks = 0; ks < 2; ++ks)
#pragma unroll
    for (int j = 0; j < 8; ++j) {
      float d = o[ks][j] - mu;
      o[ks][j] = d;
      var = fmaf(d, d, var);
    }
  var += __shfl_xor(var, 16);
  var += __shfl_xor(var, 32);
  var *= (1.0f / 64.0f);
  float rstd = rsqrtf(var + 1e-5f);

  if (col == 0) {
    const int b = g4 * 4 + wid;
    float* obase = out + ((size_t)b * N_ + n) * T_;
#pragma unroll
    for (int ks = 0; ks < 2; ++ks) {
      int tb = ks * 32 + quad * 8;
      float4 g0 = *(const float4*)(gamma + tb);
      float4 g1 = *(const float4*)(gamma + tb + 4);
      float4 b0 = *(const float4*)(beta + tb);
      float4 b1 = *(const float4*)(beta + tb + 4);
      float4 r0, r1;
      r0.x = o[ks][0] * rstd * g0.x + b0.x;
      r0.y = o[ks][1] * rstd * g0.y + b0.y;
      r0.z = o[ks][2] * rstd * g0.z + b0.z;
      r0.w = o[ks][3] * rstd * g0.w + b0.w;
      r1.x = o[ks][4] * rstd * g1.x + b1.x;
      r1.y = o[ks][5] * rstd * g1.y + b1.y;
      r1.z = o[ks][6] * rstd * g1.z + b1.z;
      r1.w = o[ks][7] * rstd * g1.w + b1.w;
      *(float4*)(obase + tb) = r0;
      *(float4*)(obase + tb + 4) = r1;
    }
  }
}

// ---------------------------------------------------------------------------
// Workspace layout (bytes):
//   Wq2    [M][N][T][pi(D)]  bf16 : off 0,           33,554,432
//   priors [N][G32][M][8][T] bf16 : off 33,554,432,  67,108,864
//   xb2    [M][B][pi(D)]     bf16 : off 100,663,296,  4,194,304
//   LHn    [L][T]            bf16 : off 104,857,600,     16,384
//   thrT   [N][M]            fp32 : off 104,873,984,      8,192
// ---------------------------------------------------------------------------
extern "C" void kernel_launch(void* const* d_in, const int* in_sizes, int n_in,
                              void* d_out, int out_size, void* d_ws, size_t ws_size,
                              hipStream_t stream) {
  const float* x = (const float*)d_in[0];
  const float* rw = (const float*)d_in[1];
  const float* thr = (const float*)d_in[2];
  const float* leaves = (const float*)d_in[3];
  const float* gamma = (const float*)d_in[4];
  const float* beta = (const float*)d_in[5];
  float* out = (float*)d_out;

  char* ws = (char*)d_ws;
  unsigned short* wq2 = (unsigned short*)(ws);
  unsigned short* priors = (unsigned short*)(ws + 33554432);
  unsigned short* xb2 = (unsigned short*)(ws + 33554432 + 67108864);
  unsigned short* lhn = (unsigned short*)(ws + 100663296 + 4194304);
  float* thrT = (float*)(ws + 104857600 + 16384);

  hipLaunchKernelGGL(k_entmax, dim3(1538), dim3(256), 0, stream, rw, wq2, x, leaves, xb2, lhn, thr, thrT);
  hipLaunchKernelGGL(k_priors, dim3(32, 64), dim3(256), 0, stream, xb2, wq2, priors);
  hipLaunchKernelGGL(k_route, dim3(32, 64), dim3(256), 0, stream, priors, lhn, thrT, gamma, beta, out);
}

// Round 12
// 185.034 us; speedup vs baseline: 1.1450x; 1.0098x over previous
//
#include <hip/hip_runtime.h>
#include <hip/hip_bf16.h>
#include <math.h>

// Problem sizes (fixed by reference): B=256, M=64, N=32, D=128, T=64, L=128
#define B_ 256
#define M_ 64
#define N_ 32
#define D_ 128
#define T_ 64
#define L_ 128

typedef __attribute__((ext_vector_type(8))) short short8;   // 8 bf16 = 4 VGPRs (MFMA A/B frag)
typedef __attribute__((ext_vector_type(4))) float floatx4;  // MFMA C/D frag

__device__ __forceinline__ unsigned short f2bf(float f) {
  unsigned int u = __float_as_uint(f);
  unsigned int r = (u + 0x7fffu + ((u >> 16) & 1u)) >> 16;  // RNE
  return (unsigned short)r;
}
__device__ __forceinline__ float bf2f(unsigned short s) {
  return __uint_as_float(((unsigned int)s) << 16);
}
__device__ __forceinline__ float frcp(float x) { return __builtin_amdgcn_rcpf(x); }

// ---------------------------------------------------------------------------
// K1 (unchanged from R11): exact entmax-1.5 over D of route_weights [M,N,D,T]
// with float4-along-T loads; wq2/xb2 rows store d in pi-permuted order
// pi(8i+j)=16j+i (consistent on both GEMM operands -> identical dot values).
// Prep paths (blocks >= 1024): xb2 pi-transposed cast, leaves norm, thrT.
// ---------------------------------------------------------------------------
__global__ __launch_bounds__(256) void k_entmax(const float* __restrict__ rw,
                                                unsigned short* __restrict__ wq2,
                                                const float* __restrict__ x,
                                                const float* __restrict__ leaves,
                                                unsigned short* __restrict__ xb2,
                                                unsigned short* __restrict__ lhn,
                                                const float* __restrict__ thr,
                                                float* __restrict__ thrT) {
  const int tid = threadIdx.x;
  const int bx = blockIdx.x;
  if (bx >= 1024) {  // prep paths
    int bid = bx - 1024;
    if (bid < 512) {
      // xb2[m][b][pi(d)] = x[b][m][d], pi(8i+j) = 16j+i
      int idx = bid * 256 + tid;         // (m, b, j)
      int j = idx & 7, b = (idx >> 3) & 255, m = idx >> 11;
      const float* xs = x + ((size_t)b * M_ + m) * D_ + j;
      unsigned short pv[16];
#pragma unroll
      for (int i = 0; i < 16; ++i) pv[i] = f2bf(xs[i * 8]);
      unsigned short* dst = xb2 + ((size_t)m * B_ + b) * D_ + j * 16;
      uint4 w0, w1;
      w0.x = pv[0] | ((unsigned)pv[1] << 16);  w0.y = pv[2] | ((unsigned)pv[3] << 16);
      w0.z = pv[4] | ((unsigned)pv[5] << 16);  w0.w = pv[6] | ((unsigned)pv[7] << 16);
      w1.x = pv[8] | ((unsigned)pv[9] << 16);  w1.y = pv[10] | ((unsigned)pv[11] << 16);
      w1.z = pv[12] | ((unsigned)pv[13] << 16); w1.w = pv[14] | ((unsigned)pv[15] << 16);
      *(uint4*)(dst) = w0;
      *(uint4*)(dst + 8) = w1;
    } else if (bid == 512) {
      if (tid < L_) {
        const float* r = leaves + tid * T_;
        float ss = 0.f;
        for (int i = 0; i < T_; ++i) ss = fmaf(r[i], r[i], ss);
        float inv = frcp(fmaxf(sqrtf(ss), 1e-12f));
        unsigned short* o = lhn + tid * T_;
        for (int i = 0; i < T_; ++i) o[i] = f2bf(r[i] * inv);
      }
    } else {  // thrT[n][m] = thr[m][n]
#pragma unroll
      for (int k = 0; k < 8; ++k) {
        int idx = k * 256 + tid;
        int nn = idx >> 6, mm = idx & 63;
        thrT[idx] = thr[mm * N_ + nn];
      }
    }
    return;
  }

  // entmax main: block covers 2 mn's; 128 threads per mn.
  const int mn = bx * 2 + (tid >> 7);
  const int sub = tid & 127;
  const int g = sub >> 3;   // t-group: lane's 4 t's are 4g..4g+3
  const int j = sub & 7;    // d-lane: d = 8i + j
  const float* base = rw + (size_t)mn * D_ * T_ + g * 4;

  floatx4 xv[16];
#pragma unroll
  for (int i = 0; i < 16; ++i)
    xv[i] = *(const floatx4*)(base + (size_t)(i * 8 + j) * T_);

  floatx4 mx = xv[0];
#pragma unroll
  for (int i = 1; i < 16; ++i)
#pragma unroll
    for (int c = 0; c < 4; ++c) mx[c] = fmaxf(mx[c], xv[i][c]);
#pragma unroll
  for (int off = 1; off <= 4; off <<= 1)
#pragma unroll
    for (int c = 0; c < 4; ++c) mx[c] = fmaxf(mx[c], __shfl_xor(mx[c], off));
#pragma unroll
  for (int i = 0; i < 16; ++i)
#pragma unroll
    for (int c = 0; c < 4; ++c) xv[i][c] = (xv[i][c] - mx[c]) * 0.5f;

  floatx4 lo = (floatx4){-1.f, -1.f, -1.f, -1.f};
  floatx4 hi = (floatx4){0.f, 0.f, 0.f, 0.f};
  for (int it = 0; it < 10; ++it) {
    floatx4 tau, f = (floatx4){0.f, 0.f, 0.f, 0.f};
#pragma unroll
    for (int c = 0; c < 4; ++c) tau[c] = 0.5f * (lo[c] + hi[c]);
#pragma unroll
    for (int i = 0; i < 16; ++i)
#pragma unroll
      for (int c = 0; c < 4; ++c) {
        float u = fmaxf(xv[i][c] - tau[c], 0.0f);
        f[c] = fmaf(u, u, f[c]);
      }
#pragma unroll
    for (int off = 1; off <= 4; off <<= 1)
#pragma unroll
      for (int c = 0; c < 4; ++c) f[c] += __shfl_xor(f[c], off);
#pragma unroll
    for (int c = 0; c < 4; ++c) {
      bool ge = f[c] >= 1.0f;
      lo[c] = ge ? tau[c] : lo[c];
      hi[c] = ge ? hi[c] : tau[c];
    }
  }
  floatx4 tau0, cnt = (floatx4){0,0,0,0}, s1 = (floatx4){0,0,0,0}, s2 = (floatx4){0,0,0,0};
#pragma unroll
  for (int c = 0; c < 4; ++c) tau0[c] = 0.5f * (lo[c] + hi[c]);
#pragma unroll
  for (int i = 0; i < 16; ++i)
#pragma unroll
    for (int c = 0; c < 4; ++c) {
      bool in = xv[i][c] > tau0[c];
      float q = in ? xv[i][c] : 0.0f;
      cnt[c] += in ? 1.0f : 0.0f;
      s1[c] += q;
      s2[c] = fmaf(q, q, s2[c]);
    }
#pragma unroll
  for (int off = 1; off <= 4; off <<= 1)
#pragma unroll
    for (int c = 0; c < 4; ++c) {
      cnt[c] += __shfl_xor(cnt[c], off);
      s1[c] += __shfl_xor(s1[c], off);
      s2[c] += __shfl_xor(s2[c], off);
    }
  floatx4 tau;
#pragma unroll
  for (int c = 0; c < 4; ++c) {
    float rc = frcp(cnt[c]);
    float mean = s1[c] * rc;
    float ss = s2[c] - mean * s1[c];
    float delta = (1.0f - ss) * rc;
    tau[c] = mean - sqrtf(fmaxf(delta, 0.0f));
  }

#pragma unroll
  for (int c = 0; c < 4; ++c) {
    unsigned short pv[16];
#pragma unroll
    for (int i = 0; i < 16; ++i) {
      float u = fmaxf(xv[i][c] - tau[c], 0.0f);
      pv[i] = f2bf(u * u);
    }
    unsigned short* dst = wq2 + ((size_t)mn * 64 + g * 4 + c) * D_ + j * 16;
    uint4 w0, w1;
    w0.x = pv[0] | ((unsigned)pv[1] << 16);  w0.y = pv[2] | ((unsigned)pv[3] << 16);
    w0.z = pv[4] | ((unsigned)pv[5] << 16);  w0.w = pv[6] | ((unsigned)pv[7] << 16);
    w1.x = pv[8] | ((unsigned)pv[9] << 16);  w1.y = pv[10] | ((unsigned)pv[11] << 16);
    w1.z = pv[12] | ((unsigned)pv[13] << 16); w1.w = pv[14] | ((unsigned)pv[15] << 16);
    *(uint4*)(dst) = w0;
    *(uint4*)(dst + 8) = w1;
  }
}

// ---------------------------------------------------------------------------
// K2 (R12): same compute as R11 (A=W from LDS, B=x up-front global loads,
// Ct transpose via ds_write_b64), but stores to priors[n][b][m][t]:
// per b one 128B contiguous chunk (2 threads) at 8KB stride. 128B = two
// full 64B lines -> no write amplification (R10's blowup was 32B granules).
// ---------------------------------------------------------------------------
#define BS_STRIDE 136
__global__ __launch_bounds__(256, 4) void k_priors(const unsigned short* __restrict__ xb2,
                                                   const unsigned short* __restrict__ wq2,
                                                   unsigned short* __restrict__ priors) {
  const int n = blockIdx.x, m = blockIdx.y;
  const int tid = threadIdx.x;
  const int wid = tid >> 6, lane = tid & 63;
  const int row16 = lane & 15, quad = lane >> 4;
  __shared__ __align__(16) unsigned short Bs[64 * BS_STRIDE];  // W [t][pi_d]
  __shared__ __align__(16) unsigned short Ct[128 * 72];        // [b][t]

  // issue ALL B-operand (x) loads first
  short8 xfr[2][2][4];
#pragma unroll
  for (int c = 0; c < 2; ++c)
#pragma unroll
    for (int sub = 0; sub < 2; ++sub) {
      const int b = c * 128 + wid * 32 + sub * 16 + row16;
      const unsigned short* xptr = xb2 + ((size_t)m * B_ + b) * D_ + quad * 8;
#pragma unroll
      for (int ks = 0; ks < 4; ++ks) xfr[c][sub][ks] = *(const short8*)(xptr + ks * 32);
    }

  {  // stage W tile into LDS
    const unsigned short* bsrc = wq2 + ((size_t)(m * N_ + n) * T_) * D_;
    int tr = tid >> 4, cc = tid & 15;
#pragma unroll
    for (int p = 0; p < 4; ++p) {
      int row = p * 16 + tr;
      uint4 v = *(const uint4*)(bsrc + row * D_ + cc * 8);
      *(uint4*)&Bs[row * BS_STRIDE + cc * 8] = v;
    }
  }
  __syncthreads();

#pragma unroll
  for (int c = 0; c < 2; ++c) {  // chunk of 128 b
    floatx4 acc[2][4];
#pragma unroll
    for (int sub = 0; sub < 2; ++sub)
#pragma unroll
      for (int cf = 0; cf < 4; ++cf) acc[sub][cf] = (floatx4){0.f, 0.f, 0.f, 0.f};

#pragma unroll
    for (int cf = 0; cf < 4; ++cf) {
      short8 afr[4];
#pragma unroll
      for (int ks = 0; ks < 4; ++ks)
        afr[ks] = *(const short8*)&Bs[(cf * 16 + row16) * BS_STRIDE + ks * 32 + quad * 8];
#pragma unroll
      for (int ks = 0; ks < 4; ++ks)
#pragma unroll
        for (int sub = 0; sub < 2; ++sub)
          acc[sub][cf] = __builtin_amdgcn_mfma_f32_16x16x32_bf16(afr[ks], xfr[c][sub][ks], acc[sub][cf], 0, 0, 0);
    }

    if (c) __syncthreads();
#pragma unroll
    for (int sub = 0; sub < 2; ++sub)
#pragma unroll
      for (int cf = 0; cf < 4; ++cf) {
        ushort4 o4;
        o4.x = f2bf(acc[sub][cf][0]); o4.y = f2bf(acc[sub][cf][1]);
        o4.z = f2bf(acc[sub][cf][2]); o4.w = f2bf(acc[sub][cf][3]);
        *(ushort4*)&Ct[(wid * 32 + sub * 16 + row16) * 72 + cf * 16 + quad * 4] = o4;
      }
    __syncthreads();

    {  // store: 2 threads per b -> one 128B contiguous chunk at 8KB stride
      int q = tid >> 4, s = tid & 15;
      int row = q * 8 + (s >> 1);      // b_local 0..127
      int half = s & 1;
      int b = c * 128 + row;
      const unsigned short* src = &Ct[row * 72 + half * 32];
      unsigned short* dst = priors + (((size_t)n * B_ + b) * M_ + m) * T_ + half * 32;
      uint4 a0 = *(const uint4*)(src);
      uint4 a1 = *(const uint4*)(src + 8);
      uint4 a2 = *(const uint4*)(src + 16);
      uint4 a3 = *(const uint4*)(src + 24);
      *(uint4*)(dst) = a0;
      *(uint4*)(dst + 8) = a1;
      *(uint4*)(dst + 16) = a2;
      *(uint4*)(dst + 24) = a3;
    }
  }
}

// ---------------------------------------------------------------------------
// K3 (R12): same wave-owns-b math as R9-R11, but priors is [n][b][m][t]:
// each wave's P matrix is ONE contiguous 8KB slab — afr loads sweep it in
// consecutive 64B lines (was 64B granules at 1KB stride: ~650 GB/s effective,
// the R11 bottleneck). No LDS staging, no barriers.
// ---------------------------------------------------------------------------
__global__ __launch_bounds__(256, 4) void k_route(const unsigned short* __restrict__ priors,
                                                  const unsigned short* __restrict__ lhn,
                                                  const float* __restrict__ thrT,
                                                  const float* __restrict__ gamma,
                                                  const float* __restrict__ beta,
                                                  float* __restrict__ out) {
  const int n = blockIdx.x, g4 = blockIdx.y;
  const int tid = threadIdx.x;
  const int wid = tid >> 6, lane = tid & 63;
  const int col = lane & 15, quad = lane >> 4;

  __shared__ float probL[4][64];

  const int b = g4 * 4 + wid;  // wave's batch element

  const unsigned short* base = priors + ((size_t)n * B_ + b) * (M_ * T_);  // 8KB contiguous
  short8 afr[4][2];  // A[m = mt*16+col][k(t) = ks*32+quad*8+j]
#pragma unroll
  for (int mt = 0; mt < 4; ++mt)
#pragma unroll
    for (int ks = 0; ks < 2; ++ks)
      afr[mt][ks] = *(const short8*)(base + (mt * 16 + col) * T_ + ks * 32 + quad * 8);

  float thv = thrT[n * 64 + lane];

  float dis[4][4];
#pragma unroll
  for (int mt = 0; mt < 4; ++mt)
#pragma unroll
    for (int r = 0; r < 4; ++r) dis[mt][r] = 0.f;

#pragma unroll
  for (int s4 = 0; s4 < 4; ++s4) {
    floatx4 acc[4][2];
#pragma unroll
    for (int mt = 0; mt < 4; ++mt)
#pragma unroll
      for (int lt = 0; lt < 2; ++lt) acc[mt][lt] = (floatx4){0.f, 0.f, 0.f, 0.f};

#pragma unroll
    for (int lt = 0; lt < 2; ++lt) {
#pragma unroll
      for (int ks = 0; ks < 2; ++ks) {
        short8 bfr = *(const short8*)(lhn + (s4 * 32 + lt * 16 + col) * T_ + ks * 32 + quad * 8);
#pragma unroll
        for (int mt = 0; mt < 4; ++mt)
          acc[mt][lt] = __builtin_amdgcn_mfma_f32_16x16x32_bf16(afr[mt][ks], bfr, acc[mt][lt], 0, 0, 0);
      }
    }

#pragma unroll
    for (int mt = 0; mt < 4; ++mt)
#pragma unroll
      for (int lt = 0; lt < 2; ++lt)
#pragma unroll
        for (int r = 0; r < 4; ++r)
          acc[mt][lt][r] = frcp(1.0f + __expf(-acc[mt][lt][r]));

    float mc[2];
#pragma unroll
    for (int lt = 0; lt < 2; ++lt) {
      float s = 0.f;
#pragma unroll
      for (int mt = 0; mt < 4; ++mt)
#pragma unroll
        for (int r = 0; r < 4; ++r) s += acc[mt][lt][r];
      s += __shfl_xor(s, 16);
      s += __shfl_xor(s, 32);
      mc[lt] = s * (1.0f / 64.0f);
    }

#pragma unroll
    for (int mt = 0; mt < 4; ++mt)
#pragma unroll
      for (int r = 0; r < 4; ++r) {
        float s = 0.f;
#pragma unroll
        for (int lt = 0; lt < 2; ++lt) {
          float df = acc[mt][lt][r] - mc[lt];
          s = fmaf(df, df, s);
        }
        dis[mt][r] += s;
      }
  }

#pragma unroll
  for (int off = 1; off <= 8; off <<= 1)
#pragma unroll
    for (int mt = 0; mt < 4; ++mt)
#pragma unroll
      for (int r = 0; r < 4; ++r) dis[mt][r] += __shfl_xor(dis[mt][r], off);

  float e[4][4];
  float mxw = 0.f;
#pragma unroll
  for (int mt = 0; mt < 4; ++mt)
#pragma unroll
    for (int r = 0; r < 4; ++r) {
      float th = __shfl(thv, mt * 16 + quad * 4 + r);
      float w = fmaxf(th * th - dis[mt][r] * (1.0f / 128.0f), 0.0f);
      e[mt][r] = w;
      mxw = fmaxf(mxw, w);
    }
  mxw = fmaxf(mxw, __shfl_xor(mxw, 16));
  mxw = fmaxf(mxw, __shfl_xor(mxw, 32));
  float ssum = 0.f;
#pragma unroll
  for (int mt = 0; mt < 4; ++mt)
#pragma unroll
    for (int r = 0; r < 4; ++r) {
      e[mt][r] = __expf(e[mt][r] - mxw);
      ssum += e[mt][r];
    }
  ssum += __shfl_xor(ssum, 16);
  ssum += __shfl_xor(ssum, 32);
  float inv = frcp(ssum);
  if (col == 0) {
#pragma unroll
    for (int mt = 0; mt < 4; ++mt)
#pragma unroll
      for (int r = 0; r < 4; ++r)
        probL[wid][mt * 16 + quad * 4 + r] = e[mt][r] * inv;
  }
  // same-wave LDS write->read: compiler inserts lgkmcnt wait (no barrier)

  float pr[4];
#pragma unroll
  for (int mt = 0; mt < 4; ++mt) pr[mt] = probL[wid][mt * 16 + col];

  float o[2][8];
#pragma unroll
  for (int ks = 0; ks < 2; ++ks)
#pragma unroll
    for (int j = 0; j < 8; ++j) o[ks][j] = 0.f;
#pragma unroll
  for (int mt = 0; mt < 4; ++mt)
#pragma unroll
    for (int ks = 0; ks < 2; ++ks)
#pragma unroll
      for (int j = 0; j < 8; ++j)
        o[ks][j] = fmaf(pr[mt], bf2f((unsigned short)afr[mt][ks][j]), o[ks][j]);
#pragma unroll
  for (int off = 1; off <= 8; off <<= 1)
#pragma unroll
    for (int ks = 0; ks < 2; ++ks)
#pragma unroll
      for (int j = 0; j < 8; ++j) o[ks][j] += __shfl_xor(o[ks][j], off);

  float mu = 0.f;
#pragma unroll
  for (int ks = 0; ks < 2; ++ks)
#pragma unroll
    for (int j = 0; j < 8; ++j) mu += o[ks][j];
  mu += __shfl_xor(mu, 16);
  mu += __shfl_xor(mu, 32);
  mu *= (1.0f / 64.0f);
  float var = 0.f;
#pragma unroll
  for (int ks = 0; ks < 2; ++ks)
#pragma unroll
    for (int j = 0; j < 8; ++j) {
      float d = o[ks][j] - mu;
      o[ks][j] = d;
      var = fmaf(d, d, var);
    }
  var += __shfl_xor(var, 16);
  var += __shfl_xor(var, 32);
  var *= (1.0f / 64.0f);
  float rstd = rsqrtf(var + 1e-5f);

  if (col == 0) {
    float* obase = out + ((size_t)b * N_ + n) * T_;
#pragma unroll
    for (int ks = 0; ks < 2; ++ks) {
      int tb = ks * 32 + quad * 8;
      float4 g0 = *(const float4*)(gamma + tb);
      float4 g1 = *(const float4*)(gamma + tb + 4);
      float4 b0 = *(const float4*)(beta + tb);
      float4 b1 = *(const float4*)(beta + tb + 4);
      float4 r0, r1;
      r0.x = o[ks][0] * rstd * g0.x + b0.x;
      r0.y = o[ks][1] * rstd * g0.y + b0.y;
      r0.z = o[ks][2] * rstd * g0.z + b0.z;
      r0.w = o[ks][3] * rstd * g0.w + b0.w;
      r1.x = o[ks][4] * rstd * g1.x + b1.x;
      r1.y = o[ks][5] * rstd * g1.y + b1.y;
      r1.z = o[ks][6] * rstd * g1.z + b1.z;
      r1.w = o[ks][7] * rstd * g1.w + b1.w;
      *(float4*)(obase + tb) = r0;
      *(float4*)(obase + tb + 4) = r1;
    }
  }
}

// ---------------------------------------------------------------------------
// Workspace layout (bytes):
//   Wq2    [M][N][T][pi(D)]  bf16 : off 0,           33,554,432
//   priors [N][B][M][T]      bf16 : off 33,554,432,  67,108,864
//   xb2    [M][B][pi(D)]     bf16 : off 100,663,296,  4,194,304
//   LHn    [L][T]            bf16 : off 104,857,600,     16,384
//   thrT   [N][M]            fp32 : off 104,873,984,      8,192
// ---------------------------------------------------------------------------
extern "C" void kernel_launch(void* const* d_in, const int* in_sizes, int n_in,
                              void* d_out, int out_size, void* d_ws, size_t ws_size,
                              hipStream_t stream) {
  const float* x = (const float*)d_in[0];
  const float* rw = (const float*)d_in[1];
  const float* thr = (const float*)d_in[2];
  const float* leaves = (const float*)d_in[3];
  const float* gamma = (const float*)d_in[4];
  const float* beta = (const float*)d_in[5];
  float* out = (float*)d_out;

  char* ws = (char*)d_ws;
  unsigned short* wq2 = (unsigned short*)(ws);
  unsigned short* priors = (unsigned short*)(ws + 33554432);
  unsigned short* xb2 = (unsigned short*)(ws + 33554432 + 67108864);
  unsigned short* lhn = (unsigned short*)(ws + 100663296 + 4194304);
  float* thrT = (float*)(ws + 104857600 + 16384);

  hipLaunchKernelGGL(k_entmax, dim3(1538), dim3(256), 0, stream, rw, wq2, x, leaves, xb2, lhn, thr, thrT);
  hipLaunchKernelGGL(k_priors, dim3(32, 64), dim3(256), 0, stream, xb2, wq2, priors);
  hipLaunchKernelGGL(k_route, dim3(32, 64), dim3(256), 0, stream, priors, lhn, thrT, gamma, beta, out);
}

// Round 13
// 178.647 us; speedup vs baseline: 1.1860x; 1.0357x over previous
//
#include <hip/hip_runtime.h>
#include <hip/hip_bf16.h>
#include <math.h>

// Problem sizes (fixed by reference): B=256, M=64, N=32, D=128, T=64, L=128
#define B_ 256
#define M_ 64
#define N_ 32
#define D_ 128
#define T_ 64
#define L_ 128

typedef __attribute__((ext_vector_type(8))) short short8;   // 8 bf16 = 4 VGPRs (MFMA A/B frag)
typedef __attribute__((ext_vector_type(4))) float floatx4;  // MFMA C/D frag

__device__ __forceinline__ unsigned short f2bf(float f) {
  unsigned int u = __float_as_uint(f);
  unsigned int r = (u + 0x7fffu + ((u >> 16) & 1u)) >> 16;  // RNE
  return (unsigned short)r;
}
__device__ __forceinline__ float bf2f(unsigned short s) {
  return __uint_as_float(((unsigned int)s) << 16);
}
__device__ __forceinline__ float frcp(float x) { return __builtin_amdgcn_rcpf(x); }

// ---------------------------------------------------------------------------
// K0: prep. blocks < 2048: x -> bf16 transposed xb2[M][B][D] (straight d —
// the pi permutation died with wq2). block 2048: leaves norm. 2049: thrT.
// ---------------------------------------------------------------------------
__global__ __launch_bounds__(256) void k_prep(const float* __restrict__ x,
                                              const float* __restrict__ leaves,
                                              unsigned short* __restrict__ xb2,
                                              unsigned short* __restrict__ lhn,
                                              const float* __restrict__ thr,
                                              float* __restrict__ thrT) {
  const int tid = threadIdx.x;
  const int bx = blockIdx.x;
  if (bx < 2048) {
    size_t e = ((size_t)bx * 256 + tid) * 4;
    int b = (int)(e >> 13);        // / (M*D = 8192)
    int rem = (int)(e & 8191);
    int mm = rem >> 7, dd = rem & 127;
    float4 v = *(const float4*)(x + e);
    ushort4 o;
    o.x = f2bf(v.x); o.y = f2bf(v.y); o.z = f2bf(v.z); o.w = f2bf(v.w);
    *(ushort4*)(xb2 + ((size_t)mm * B_ + b) * D_ + dd) = o;
  } else if (bx == 2048) {
    if (tid < L_) {
      const float* r = leaves + tid * T_;
      float ss = 0.f;
      for (int i = 0; i < T_; ++i) ss = fmaf(r[i], r[i], ss);
      float inv = frcp(fmaxf(sqrtf(ss), 1e-12f));
      unsigned short* o = lhn + tid * T_;
      for (int i = 0; i < T_; ++i) o[i] = f2bf(r[i] * inv);
    }
  } else {  // thrT[n][m] = thr[m][n]
#pragma unroll
    for (int k = 0; k < 8; ++k) {
      int idx = k * 256 + tid;
      int nn = idx >> 6, mm = idx & 63;
      thrT[idx] = thr[mm * N_ + nn];
    }
  }
}

// ---------------------------------------------------------------------------
// K1 (R13 fusion): entmax + priors GEMM in ONE kernel. Block = (m,n):
//  1. xfr: all 16 B-operand (x) global loads issued up-front.
//  2. stage rw[m][n] tile (contiguous 32KB fp32) -> LDS rwT[d][t].
//  3. in-block entmax-1.5 (4 threads/vector: t=tid>>2, q=tid&3; 10 bisections
//     + exact solve on support — the R6-R12-proven math, source = LDS) ->
//     weights written bf16 straight into the Bs MFMA A-tile.
//  4. GEMM (A=W from Bs, B=x regs) -> C[row=t][col=b]; Ct transpose (aliases
//     rwT — dead after entmax) -> 128B-contiguous stores to priors[n][b][m][t].
// Kills the 32MB wq2 write + 33MB read + one kernel launch.
// LDS: rwT/Ct union 32KB + Bs 17.4KB = 49.4KB -> 3 blocks/CU.
// ---------------------------------------------------------------------------
#define BS_STRIDE 136
__global__ __launch_bounds__(256, 3) void k_wpriors(const unsigned short* __restrict__ xb2,
                                                    const float* __restrict__ rw,
                                                    unsigned short* __restrict__ priors) {
  const int m = blockIdx.x, n = blockIdx.y;
  const int tid = threadIdx.x;
  const int wid = tid >> 6, lane = tid & 63;
  const int row16 = lane & 15, quad = lane >> 4;

  __shared__ __align__(16) float rwT[8192];                    // [d][t] fp32; Ct aliases
  __shared__ __align__(16) unsigned short Bs[64 * BS_STRIDE];  // W [t][d] bf16
  unsigned short* Ct = (unsigned short*)rwT;                   // [b_local][t] (72 stride)

  // 1. all B-operand (x) loads up-front: b = c*128 + wid*32 + sub*16 + row16
  short8 xfr[2][2][4];
#pragma unroll
  for (int c = 0; c < 2; ++c)
#pragma unroll
    for (int sub = 0; sub < 2; ++sub) {
      const int b = c * 128 + wid * 32 + sub * 16 + row16;
      const unsigned short* xptr = xb2 + ((size_t)m * B_ + b) * D_ + quad * 8;
#pragma unroll
      for (int ks = 0; ks < 4; ++ks) xfr[c][sub][ks] = *(const short8*)(xptr + ks * 32);
    }

  // 2. stage rw tile: one contiguous 32KB slab
  {
    const float* src = rw + ((size_t)(m * N_ + n)) * (D_ * T_);
#pragma unroll
    for (int i = 0; i < 8; ++i) {
      int idx = i * 256 + tid;  // float4 slot 0..2047
      *(float4*)&rwT[idx * 4] = *(const float4*)(src + idx * 4);
    }
  }
  __syncthreads();

  // 3. entmax over d for vector t (t = tid>>2, quarter q = tid&3)
  {
    const int t = tid >> 2, q = tid & 3;
    float xv[32];
#pragma unroll
    for (int i = 0; i < 32; ++i) xv[i] = rwT[(q * 32 + i) * 64 + t];
    float mx = xv[0];
#pragma unroll
    for (int i = 1; i < 32; ++i) mx = fmaxf(mx, xv[i]);
    mx = fmaxf(mx, __shfl_xor(mx, 1));
    mx = fmaxf(mx, __shfl_xor(mx, 2));
#pragma unroll
    for (int i = 0; i < 32; ++i) xv[i] = (xv[i] - mx) * 0.5f;

    float lo = -1.0f, hi = 0.0f;
    for (int it = 0; it < 10; ++it) {
      float tau = 0.5f * (lo + hi);
      float f0 = 0.f, f1 = 0.f;
#pragma unroll
      for (int i = 0; i < 16; ++i) {
        float u0 = fmaxf(xv[2 * i] - tau, 0.0f);
        float u1 = fmaxf(xv[2 * i + 1] - tau, 0.0f);
        f0 = fmaf(u0, u0, f0);
        f1 = fmaf(u1, u1, f1);
      }
      float f = f0 + f1;
      f += __shfl_xor(f, 1);
      f += __shfl_xor(f, 2);
      if (f >= 1.0f) lo = tau; else hi = tau;
    }
    float tau0 = 0.5f * (lo + hi);
    float cnt = 0.f, s1 = 0.f, s2 = 0.f;
#pragma unroll
    for (int i = 0; i < 32; ++i) {
      bool in = xv[i] > tau0;
      float qv = in ? xv[i] : 0.0f;
      cnt += in ? 1.0f : 0.0f;
      s1 += qv;
      s2 = fmaf(qv, qv, s2);
    }
    cnt += __shfl_xor(cnt, 1); cnt += __shfl_xor(cnt, 2);
    s1 += __shfl_xor(s1, 1);   s1 += __shfl_xor(s1, 2);
    s2 += __shfl_xor(s2, 1);   s2 += __shfl_xor(s2, 2);
    float rc = frcp(cnt);
    float mean = s1 * rc;
    float ss = s2 - mean * s1;
    float delta = (1.0f - ss) * rc;
    float tau = mean - sqrtf(fmaxf(delta, 0.0f));

    unsigned short pv[32];
#pragma unroll
    for (int i = 0; i < 32; ++i) {
      float u = fmaxf(xv[i] - tau, 0.0f);
      pv[i] = f2bf(u * u);
    }
    // straight-d store into the MFMA A-tile: Bs[t][q*32 .. q*32+31]
    uint4* dst = (uint4*)&Bs[t * BS_STRIDE + q * 32];
#pragma unroll
    for (int j = 0; j < 4; ++j) {
      uint4 w;
      w.x = (unsigned)pv[8 * j + 0] | ((unsigned)pv[8 * j + 1] << 16);
      w.y = (unsigned)pv[8 * j + 2] | ((unsigned)pv[8 * j + 3] << 16);
      w.z = (unsigned)pv[8 * j + 4] | ((unsigned)pv[8 * j + 5] << 16);
      w.w = (unsigned)pv[8 * j + 6] | ((unsigned)pv[8 * j + 7] << 16);
      dst[j] = w;
    }
  }
  __syncthreads();  // entmax done: Bs ready, rwT dead (Ct may now reuse it)

  // 4. GEMM + transpose-store (R12-proven structure)
#pragma unroll
  for (int c = 0; c < 2; ++c) {  // chunk of 128 b
    floatx4 acc[2][4];
#pragma unroll
    for (int sub = 0; sub < 2; ++sub)
#pragma unroll
      for (int cf = 0; cf < 4; ++cf) acc[sub][cf] = (floatx4){0.f, 0.f, 0.f, 0.f};

#pragma unroll
    for (int cf = 0; cf < 4; ++cf) {
      short8 afr[4];
#pragma unroll
      for (int ks = 0; ks < 4; ++ks)
        afr[ks] = *(const short8*)&Bs[(cf * 16 + row16) * BS_STRIDE + ks * 32 + quad * 8];
#pragma unroll
      for (int ks = 0; ks < 4; ++ks)
#pragma unroll
        for (int sub = 0; sub < 2; ++sub)
          acc[sub][cf] = __builtin_amdgcn_mfma_f32_16x16x32_bf16(afr[ks], xfr[c][sub][ks], acc[sub][cf], 0, 0, 0);
    }

    if (c) __syncthreads();  // chunk-0 store phase must be done with Ct
    // Ct write: lane holds t = cf*16+quad*4..+3 for b_local = wid*32+sub*16+row16
#pragma unroll
    for (int sub = 0; sub < 2; ++sub)
#pragma unroll
      for (int cf = 0; cf < 4; ++cf) {
        ushort4 o4;
        o4.x = f2bf(acc[sub][cf][0]); o4.y = f2bf(acc[sub][cf][1]);
        o4.z = f2bf(acc[sub][cf][2]); o4.w = f2bf(acc[sub][cf][3]);
        *(ushort4*)&Ct[(wid * 32 + sub * 16 + row16) * 72 + cf * 16 + quad * 4] = o4;
      }
    __syncthreads();

    {  // store: 2 threads per b -> one 128B contiguous chunk at 8KB stride
      int q = tid >> 4, s = tid & 15;
      int row = q * 8 + (s >> 1);      // b_local 0..127
      int half = s & 1;
      int b = c * 128 + row;
      const unsigned short* src = &Ct[row * 72 + half * 32];
      unsigned short* dst = priors + (((size_t)n * B_ + b) * M_ + m) * T_ + half * 32;
      uint4 a0 = *(const uint4*)(src);
      uint4 a1 = *(const uint4*)(src + 8);
      uint4 a2 = *(const uint4*)(src + 16);
      uint4 a3 = *(const uint4*)(src + 24);
      *(uint4*)(dst) = a0;
      *(uint4*)(dst + 8) = a1;
      *(uint4*)(dst + 16) = a2;
      *(uint4*)(dst + 24) = a3;
    }
  }
}

// ---------------------------------------------------------------------------
// K2 (unchanged R12): block = (n, g4); wave owns ONE b; priors[n][b][m][t]
// gives each wave ONE contiguous 8KB slab. No LDS staging, no barriers;
// rcp sigmoid/softmax; weighted sum reuses afr registers.
// ---------------------------------------------------------------------------
__global__ __launch_bounds__(256, 4) void k_route(const unsigned short* __restrict__ priors,
                                                  const unsigned short* __restrict__ lhn,
                                                  const float* __restrict__ thrT,
                                                  const float* __restrict__ gamma,
                                                  const float* __restrict__ beta,
                                                  float* __restrict__ out) {
  const int n = blockIdx.x, g4 = blockIdx.y;
  const int tid = threadIdx.x;
  const int wid = tid >> 6, lane = tid & 63;
  const int col = lane & 15, quad = lane >> 4;

  __shared__ float probL[4][64];

  const int b = g4 * 4 + wid;  // wave's batch element

  const unsigned short* base = priors + ((size_t)n * B_ + b) * (M_ * T_);  // 8KB contiguous
  short8 afr[4][2];  // A[m = mt*16+col][k(t) = ks*32+quad*8+j]
#pragma unroll
  for (int mt = 0; mt < 4; ++mt)
#pragma unroll
    for (int ks = 0; ks < 2; ++ks)
      afr[mt][ks] = *(const short8*)(base + (mt * 16 + col) * T_ + ks * 32 + quad * 8);

  float thv = thrT[n * 64 + lane];

  float dis[4][4];
#pragma unroll
  for (int mt = 0; mt < 4; ++mt)
#pragma unroll
    for (int r = 0; r < 4; ++r) dis[mt][r] = 0.f;

#pragma unroll
  for (int s4 = 0; s4 < 4; ++s4) {
    floatx4 acc[4][2];
#pragma unroll
    for (int mt = 0; mt < 4; ++mt)
#pragma unroll
      for (int lt = 0; lt < 2; ++lt) acc[mt][lt] = (floatx4){0.f, 0.f, 0.f, 0.f};

#pragma unroll
    for (int lt = 0; lt < 2; ++lt) {
#pragma unroll
      for (int ks = 0; ks < 2; ++ks) {
        short8 bfr = *(const short8*)(lhn + (s4 * 32 + lt * 16 + col) * T_ + ks * 32 + quad * 8);
#pragma unroll
        for (int mt = 0; mt < 4; ++mt)
          acc[mt][lt] = __builtin_amdgcn_mfma_f32_16x16x32_bf16(afr[mt][ks], bfr, acc[mt][lt], 0, 0, 0);
      }
    }

#pragma unroll
    for (int mt = 0; mt < 4; ++mt)
#pragma unroll
      for (int lt = 0; lt < 2; ++lt)
#pragma unroll
        for (int r = 0; r < 4; ++r)
          acc[mt][lt][r] = frcp(1.0f + __expf(-acc[mt][lt][r]));

    float mc[2];
#pragma unroll
    for (int lt = 0; lt < 2; ++lt) {
      float s = 0.f;
#pragma unroll
      for (int mt = 0; mt < 4; ++mt)
#pragma unroll
        for (int r = 0; r < 4; ++r) s += acc[mt][lt][r];
      s += __shfl_xor(s, 16);
      s += __shfl_xor(s, 32);
      mc[lt] = s * (1.0f / 64.0f);
    }

#pragma unroll
    for (int mt = 0; mt < 4; ++mt)
#pragma unroll
      for (int r = 0; r < 4; ++r) {
        float s = 0.f;
#pragma unroll
        for (int lt = 0; lt < 2; ++lt) {
          float df = acc[mt][lt][r] - mc[lt];
          s = fmaf(df, df, s);
        }
        dis[mt][r] += s;
      }
  }

#pragma unroll
  for (int off = 1; off <= 8; off <<= 1)
#pragma unroll
    for (int mt = 0; mt < 4; ++mt)
#pragma unroll
      for (int r = 0; r < 4; ++r) dis[mt][r] += __shfl_xor(dis[mt][r], off);

  float e[4][4];
  float mxw = 0.f;
#pragma unroll
  for (int mt = 0; mt < 4; ++mt)
#pragma unroll
    for (int r = 0; r < 4; ++r) {
      float th = __shfl(thv, mt * 16 + quad * 4 + r);
      float w = fmaxf(th * th - dis[mt][r] * (1.0f / 128.0f), 0.0f);
      e[mt][r] = w;
      mxw = fmaxf(mxw, w);
    }
  mxw = fmaxf(mxw, __shfl_xor(mxw, 16));
  mxw = fmaxf(mxw, __shfl_xor(mxw, 32));
  float ssum = 0.f;
#pragma unroll
  for (int mt = 0; mt < 4; ++mt)
#pragma unroll
    for (int r = 0; r < 4; ++r) {
      e[mt][r] = __expf(e[mt][r] - mxw);
      ssum += e[mt][r];
    }
  ssum += __shfl_xor(ssum, 16);
  ssum += __shfl_xor(ssum, 32);
  float inv = frcp(ssum);
  if (col == 0) {
#pragma unroll
    for (int mt = 0; mt < 4; ++mt)
#pragma unroll
      for (int r = 0; r < 4; ++r)
        probL[wid][mt * 16 + quad * 4 + r] = e[mt][r] * inv;
  }
  // same-wave LDS write->read: compiler inserts lgkmcnt wait (no barrier)

  float pr[4];
#pragma unroll
  for (int mt = 0; mt < 4; ++mt) pr[mt] = probL[wid][mt * 16 + col];

  float o[2][8];
#pragma unroll
  for (int ks = 0; ks < 2; ++ks)
#pragma unroll
    for (int j = 0; j < 8; ++j) o[ks][j] = 0.f;
#pragma unroll
  for (int mt = 0; mt < 4; ++mt)
#pragma unroll
    for (int ks = 0; ks < 2; ++ks)
#pragma unroll
      for (int j = 0; j < 8; ++j)
        o[ks][j] = fmaf(pr[mt], bf2f((unsigned short)afr[mt][ks][j]), o[ks][j]);
#pragma unroll
  for (int off = 1; off <= 8; off <<= 1)
#pragma unroll
    for (int ks = 0; ks < 2; ++ks)
#pragma unroll
      for (int j = 0; j < 8; ++j) o[ks][j] += __shfl_xor(o[ks][j], off);

  float mu = 0.f;
#pragma unroll
  for (int ks = 0; ks < 2; ++ks)
#pragma unroll
    for (int j = 0; j < 8; ++j) mu += o[ks][j];
  mu += __shfl_xor(mu, 16);
  mu += __shfl_xor(mu, 32);
  mu *= (1.0f / 64.0f);
  float var = 0.f;
#pragma unroll
  for (int ks = 0; ks < 2; ++ks)
#pragma unroll
    for (int j = 0; j < 8; ++j) {
      float d = o[ks][j] - mu;
      o[ks][j] = d;
      var = fmaf(d, d, var);
    }
  var += __shfl_xor(var, 16);
  var += __shfl_xor(var, 32);
  var *= (1.0f / 64.0f);
  float rstd = rsqrtf(var + 1e-5f);

  if (col == 0) {
    float* obase = out + ((size_t)b * N_ + n) * T_;
#pragma unroll
    for (int ks = 0; ks < 2; ++ks) {
      int tb = ks * 32 + quad * 8;
      float4 g0 = *(const float4*)(gamma + tb);
      float4 g1 = *(const float4*)(gamma + tb + 4);
      float4 b0 = *(const float4*)(beta + tb);
      float4 b1 = *(const float4*)(beta + tb + 4);
      float4 r0, r1;
      r0.x = o[ks][0] * rstd * g0.x + b0.x;
      r0.y = o[ks][1] * rstd * g0.y + b0.y;
      r0.z = o[ks][2] * rstd * g0.z + b0.z;
      r0.w = o[ks][3] * rstd * g0.w + b0.w;
      r1.x = o[ks][4] * rstd * g1.x + b1.x;
      r1.y = o[ks][5] * rstd * g1.y + b1.y;
      r1.z = o[ks][6] * rstd * g1.z + b1.z;
      r1.w = o[ks][7] * rstd * g1.w + b1.w;
      *(float4*)(obase + tb) = r0;
      *(float4*)(obase + tb + 4) = r1;
    }
  }
}

// ---------------------------------------------------------------------------
// Workspace layout (bytes):
//   priors [N][B][M][T] bf16 : off 0,          67,108,864
//   xb2    [M][B][D]    bf16 : off 67,108,864,  4,194,304
//   LHn    [L][T]       bf16 : off 71,303,168,     16,384
//   thrT   [N][M]       fp32 : off 71,319,552,      8,192
// ---------------------------------------------------------------------------
extern "C" void kernel_launch(void* const* d_in, const int* in_sizes, int n_in,
                              void* d_out, int out_size, void* d_ws, size_t ws_size,
                              hipStream_t stream) {
  const float* x = (const float*)d_in[0];
  const float* rw = (const float*)d_in[1];
  const float* thr = (const float*)d_in[2];
  const float* leaves = (const float*)d_in[3];
  const float* gamma = (const float*)d_in[4];
  const float* beta = (const float*)d_in[5];
  float* out = (float*)d_out;

  char* ws = (char*)d_ws;
  unsigned short* priors = (unsigned short*)(ws);
  unsigned short* xb2 = (unsigned short*)(ws + 67108864);
  unsigned short* lhn = (unsigned short*)(ws + 71303168);
  float* thrT = (float*)(ws + 71319552);

  hipLaunchKernelGGL(k_prep, dim3(2050), dim3(256), 0, stream, x, leaves, xb2, lhn, thr, thrT);
  hipLaunchKernelGGL(k_wpriors, dim3(64, 32), dim3(256), 0, stream, xb2, rw, priors);
  hipLaunchKernelGGL(k_route, dim3(32, 64), dim3(256), 0, stream, priors, lhn, thrT, gamma, beta, out);
}